// Round 8
// baseline (947.610 us; speedup 1.0000x reference)
//
#include <hip/hip_runtime.h>

#define TT 200
#define BB 256
#define DD 128
#define HH 128
#define NG 896    // 7*H semantic gate dim
#define NGP 1024  // padded: pcol = u*8 + gate, gate 7 = zero pad

typedef _Float16 half8 __attribute__((ext_vector_type(8)));
typedef _Float16 half4 __attribute__((ext_vector_type(4)));
typedef float float4v __attribute__((ext_vector_type(4)));

__device__ __forceinline__ float rcpf_(float x) { return __builtin_amdgcn_rcpf(x); }
__device__ __forceinline__ float sigmoidf_(float x) { return rcpf_(1.f + __expf(-x)); }
__device__ __forceinline__ float tanhf_(float x) { return 1.f - 2.f * rcpf_(__expf(2.f * x) + 1.f); }
// softplus(x) = max(x,0) + ln(1+exp(-|x|))
__device__ __forceinline__ float softplusf_(float x) {
  return fmaxf(x, 0.f) + 0.69314718056f * __log2f(1.f + __expf(-fabsf(x)));
}

// Weight prep: WxTp[pcol][k] (pcol=u*8+g, padded), WhT[col][k] (semantic), bias_p[pcol]
__global__ __launch_bounds__(256) void wtrans_k(const float* __restrict__ Wx,
    const float* __restrict__ Wh, const float* __restrict__ bias,
    _Float16* __restrict__ WxTp, _Float16* __restrict__ WhT, float* __restrict__ bias_p) {
  int idx = blockIdx.x * 256 + threadIdx.x;
  if (idx < NGP * DD) {  // WxTp
    int pcol = idx >> 7, k = idx & 127;
    int u = pcol >> 3, g = pcol & 7;
    WxTp[idx] = (g < 7) ? (_Float16)Wx[k * NG + g * HH + u] : (_Float16)0.f;
  } else if (idx < NGP * DD + NG * DD) {  // WhT
    int i2 = idx - NGP * DD;
    int col = i2 >> 7, k = i2 & 127;
    WhT[i2] = (_Float16)Wh[k * NG + col];
  } else if (idx < NGP * DD + NG * DD + NGP) {  // bias_p
    int pcol = idx - NGP * DD - NG * DD;
    int u = pcol >> 3, g = pcol & 7;
    bias_p[pcol] = (g < 7) ? bias[g * HH + u] : 0.f;
  }
}

// xg GEMM, A-tile staged once per block (coalesced), nt-loop inside.
__global__ __launch_bounds__(256, 2) void xg_gemm_k(const float* __restrict__ x,
    const _Float16* __restrict__ WxTp, const float* __restrict__ bias_p,
    _Float16* __restrict__ xg, int t0) {
  int mt = blockIdx.x;
  __shared__ _Float16 Ald[128][136];
  __shared__ _Float16 Bld[128][136];
  int tid = threadIdx.x;
  int G0 = mt * 128;
  int t = t0 + (G0 >> 8);
  int b0 = G0 & 255;
  {  // coalesced f32 load of x[b0..b0+128)[t][0..128) -> f16 in Ald
    int r = tid >> 5, kq = (tid & 31) << 2;
#pragma unroll
    for (int it = 0; it < 16; ++it) {
      int row = r + it * 8;
      float4v xv = *(const float4v*)(x + ((size_t)(b0 + row) * TT + t) * DD + kq);
      half4 h4 = {(_Float16)xv[0], (_Float16)xv[1], (_Float16)xv[2], (_Float16)xv[3]};
      *(half4*)&Ald[row][kq] = h4;
    }
  }
  __syncthreads();
  int wv = tid >> 6, l = tid & 63, lr = l & 15, lk8 = (l >> 4) << 3;
  half8 af[2][4];
#pragma unroll
  for (int mf = 0; mf < 2; ++mf)
#pragma unroll
    for (int kk = 0; kk < 4; ++kk)
      af[mf][kk] = *(const half8*)&Ald[wv * 32 + mf * 16 + lr][kk * 32 + lk8];

  for (int nt = 0; nt < 8; ++nt) {
    for (int i = tid; i < 128 * 16; i += 256) {
      int r = i >> 4, c8 = (i & 15) << 3;
      *(half8*)&Bld[r][c8] = *(const half8*)(WxTp + (size_t)(nt * 128 + r) * DD + c8);
    }
    __syncthreads();
    float4v acc[2][8];
#pragma unroll
    for (int a = 0; a < 2; ++a)
#pragma unroll
      for (int q = 0; q < 8; ++q) acc[a][q] = (float4v){0.f, 0.f, 0.f, 0.f};
#pragma unroll
    for (int kk = 0; kk < 4; ++kk) {
#pragma unroll
      for (int nf = 0; nf < 8; ++nf) {
        half8 bv = *(const half8*)&Bld[nf * 16 + lr][kk * 32 + lk8];
        acc[0][nf] = __builtin_amdgcn_mfma_f32_16x16x32_f16(af[0][kk], bv, acc[0][nf], 0, 0, 0);
        acc[1][nf] = __builtin_amdgcn_mfma_f32_16x16x32_f16(af[1][kk], bv, acc[1][nf], 0, 0, 0);
      }
    }
    int r4 = (l >> 4) << 2;
#pragma unroll
    for (int nf = 0; nf < 8; ++nf) {
      int col = nt * 128 + nf * 16 + lr;
      float bv = bias_p[col];
#pragma unroll
      for (int mf = 0; mf < 2; ++mf) {
        int row = G0 + wv * 32 + mf * 16 + r4;
#pragma unroll
        for (int rr = 0; rr < 4; ++rr) {
          xg[(size_t)(row + rr) * NGP + col] = (_Float16)(acc[mf][nf][rr] + bv);
        }
      }
    }
    __syncthreads();  // before next nt overwrites Bld
  }
}

// MFMA recurrence, TWO samples per block for SIMD-level TLP.
// 1024 threads = 16 waves = 4 waves/SIMD (2 from each sample-group; the two
// groups' dependency chains are independent between barriers -> latency hiding).
// NOTE: __launch_bounds__(1024) with NO min-occupancy arg — round 7 used
// (1024,4) which capped regs at 128/wave and spilled wb to scratch (21 MB
// WRITE_SIZE, 5.5x regression). Weights must stay register-resident.
__global__ __launch_bounds__(1024) void rec_k(const _Float16* __restrict__ xg,
    const float* __restrict__ dur, const int* __restrict__ rep,
    const _Float16* __restrict__ WhT, float* __restrict__ out,
    _Float16* __restrict__ st_h, float* __restrict__ st_c, float* __restrict__ st_cb,
    int t0, int t1) {
  int tid = threadIdx.x;
  int s = tid >> 9, j = tid & 511;
  int b0 = blockIdx.x * 2;
  int b = b0 + s;
  int tendA = rep[b0], tendB = rep[b0 + 1];
  int tmax = max(tendA, tendB);
  if (t0 > tmax) return;  // block-uniform
  int tend = s == 0 ? tendA : tendB;
  int tstop = min(t1 - 1, tmax);
  __shared__ __align__(16) _Float16 hbuf[2][2][HH];  // [sample][buf][unit]
  __shared__ float dlds[2][TT];
  int w = j >> 6, l = j & 63, lr = l & 15, lg = l >> 4;
  int u = w * 16 + lr;

  // B-fragments: wb[tt][kk] = WhT[col = tt*128+u][k = kk*32 + lg*8 .. +8]
  half8 wb[7][4];
#pragma unroll
  for (int tt = 0; tt < 7; ++tt) {
#pragma unroll
    for (int kk = 0; kk < 4; ++kk)
      wb[tt][kk] = *(const half8*)(WhT + (size_t)(tt * HH + u) * DD + kk * 32 + lg * 8);
  }
  if (tid < 2 * TT) {
    int ss = tid / TT, ii = tid % TT;
    dlds[ss][ii] = dur[(b0 + ss) * TT + ii];
  }
  float c_s = 0.f, cb_s = 0.f;
  if (lg == 0) {
    if (t0 == 0) {
      hbuf[s][0][u] = (_Float16)0.f;
    } else {
      hbuf[s][0][u] = st_h[b * HH + u];
    }
    hbuf[s][1][u] = (_Float16)0.f;
  }
  if (t0 != 0) {
    c_s = st_c[b * HH + u];
    cb_s = st_cb[b * HH + u];
  }
  __syncthreads();

  const _Float16* xgp = xg + (size_t)b * NGP + u * 8;  // + step*stp, aligned 16B
  const size_t stp = (size_t)BB * NGP;
  half8 cur0, cur1, nxt0, nxt1;
  cur0 = *(const half8*)(xgp);
  cur1 = *(const half8*)(xgp + (size_t)(min(t0 + 1, tstop) - t0) * stp);
  float hsave = 0.f;

#define STEP(T, CUR, PIN, POUT)                                                  \
  do {                                                                           \
    float dt = dlds[s][T];                                                       \
    half8 af[4];                                                                 \
    _Pragma("unroll") for (int kk = 0; kk < 4; ++kk)                             \
        af[kk] = *(const half8*)((const char*)hbuf[s][PIN] + kk * 64 + lg * 16); \
    float4v acc[7];                                                              \
    _Pragma("unroll") for (int tt = 0; tt < 7; ++tt) {                           \
      float xv = (float)CUR[tt];                                                 \
      acc[tt] = (float4v){xv, xv, xv, xv};                                       \
    }                                                                            \
    _Pragma("unroll") for (int kk = 0; kk < 4; ++kk)                             \
        _Pragma("unroll") for (int tt = 0; tt < 7; ++tt)                         \
            acc[tt] = __builtin_amdgcn_mfma_f32_16x16x32_f16(af[kk], wb[tt][kk], \
                                                             acc[tt], 0, 0, 0);  \
    float iv = sigmoidf_(acc[0][0]), fv = sigmoidf_(acc[1][0]);                  \
    float zv = tanhf_(acc[2][0]), ov = sigmoidf_(acc[3][0]);                     \
    float ibv = sigmoidf_(acc[4][0]), fbv = sigmoidf_(acc[5][0]);                \
    float dv = softplusf_(acc[6][0]);                                            \
    float cc = fv * c_s + iv * zv;                                               \
    cb_s = fbv * cb_s + ibv * zv;                                                \
    float cn = cb_s + (cc - cb_s) * __expf(-dv * dt);                            \
    float hn = ov * tanhf_(cn);                                                  \
    c_s = cn;                                                                    \
    hsave = hn;                                                                  \
    if (lg == 0) {                                                               \
      if ((T) == tend) {                                                         \
        out[b * HH + u] = hn;                                                    \
        out[BB * HH + b * HH + u] = cn;                                          \
      }                                                                          \
      hbuf[s][POUT][u] = (_Float16)hn;                                           \
    }                                                                            \
    __syncthreads();                                                             \
  } while (0)

  for (int tb = t0; tb <= tstop; tb += 2) {
    int tp2 = min(tb + 2, tstop) - t0, tp3 = min(tb + 3, tstop) - t0;
    nxt0 = *(const half8*)(xgp + (size_t)tp2 * stp);
    nxt1 = *(const half8*)(xgp + (size_t)tp3 * stp);
    STEP(tb, cur0, 0, 1);
    if (tb + 1 <= tstop) STEP(tb + 1, cur1, 1, 0);
    cur0 = nxt0;
    cur1 = nxt1;
  }
#undef STEP

  if (tstop < tend && lg == 0) {  // save state for next chunk
    st_h[b * HH + u] = (_Float16)hsave;
    st_c[b * HH + u] = c_s;
    st_cb[b * HH + u] = cb_s;
  }
}

extern "C" void kernel_launch(void* const* d_in, const int* in_sizes, int n_in,
                              void* d_out, int out_size, void* d_ws, size_t ws_size,
                              hipStream_t stream) {
  const float* x = (const float*)d_in[0];
  const float* dur = (const float*)d_in[1];
  const int* rep = (const int*)d_in[2];
  const float* Wx = (const float*)d_in[3];
  const float* Wh = (const float*)d_in[4];
  const float* bias = (const float*)d_in[5];
  float* out = (float*)d_out;
  char* ws = (char*)d_ws;

  size_t off = 0;
  _Float16* WxTp = (_Float16*)(ws + off); off += (size_t)NGP * DD * 2;
  _Float16* WhT = (_Float16*)(ws + off); off += (size_t)NG * DD * 2;
  float* bias_p = (float*)(ws + off); off += (size_t)NGP * 4;
  _Float16* st_h = (_Float16*)(ws + off); off += (size_t)BB * HH * 2;
  float* st_c = (float*)(ws + off); off += (size_t)BB * HH * 4;
  float* st_cb = (float*)(ws + off); off += (size_t)BB * HH * 4;
  _Float16* xgbuf = (_Float16*)(ws + off);

  size_t avail = ws_size > off ? ws_size - off : 0;
  size_t perT = (size_t)BB * NGP * 2;
  int Tc = (int)(avail / perT);
  if (Tc > TT) Tc = TT;
  if (Tc < 1) Tc = 1;

  int nprep = NGP * DD + NG * DD + NGP;
  hipLaunchKernelGGL(wtrans_k, dim3((nprep + 255) / 256), dim3(256), 0, stream,
                     Wx, Wh, bias, WxTp, WhT, bias_p);
  for (int t0 = 0; t0 < TT; t0 += Tc) {
    int t1 = t0 + Tc;
    if (t1 > TT) t1 = TT;
    int mtiles = (t1 - t0) * BB / 128;
    hipLaunchKernelGGL(xg_gemm_k, dim3(mtiles), dim3(256), 0, stream,
                       x, WxTp, bias_p, xgbuf, t0);
    hipLaunchKernelGGL(rec_k, dim3(BB / 2), dim3(1024), 0, stream,
                       xgbuf, dur, rep, WhT, out, st_h, st_c, st_cb, t0, t1);
  }
}

// Round 9
// 197.853 us; speedup vs baseline: 4.7895x; 4.7895x over previous
//
#include <hip/hip_runtime.h>

#define TT 200
#define BB 256
#define DD 128
#define HH 128
#define NG 896    // 7*H semantic gate dim
#define NGP 1024  // padded: pcol = u*8 + gate, gate 7 = zero pad

typedef _Float16 half8 __attribute__((ext_vector_type(8)));
typedef _Float16 half4 __attribute__((ext_vector_type(4)));
typedef float float4v __attribute__((ext_vector_type(4)));

__device__ __forceinline__ float rcpf_(float x) { return __builtin_amdgcn_rcpf(x); }
__device__ __forceinline__ float sigmoidf_(float x) { return rcpf_(1.f + __expf(-x)); }
__device__ __forceinline__ float tanhf_(float x) { return 1.f - 2.f * rcpf_(__expf(2.f * x) + 1.f); }
// softplus(x) = max(x,0) + ln(1+exp(-|x|))
__device__ __forceinline__ float softplusf_(float x) {
  return fmaxf(x, 0.f) + 0.69314718056f * __log2f(1.f + __expf(-fabsf(x)));
}

// Weight prep: WxTp[pcol][k] (pcol=u*8+g, padded), WhT[col][k] (semantic), bias_p[pcol]
__global__ __launch_bounds__(256) void wtrans_k(const float* __restrict__ Wx,
    const float* __restrict__ Wh, const float* __restrict__ bias,
    _Float16* __restrict__ WxTp, _Float16* __restrict__ WhT, float* __restrict__ bias_p) {
  int idx = blockIdx.x * 256 + threadIdx.x;
  if (idx < NGP * DD) {  // WxTp
    int pcol = idx >> 7, k = idx & 127;
    int u = pcol >> 3, g = pcol & 7;
    WxTp[idx] = (g < 7) ? (_Float16)Wx[k * NG + g * HH + u] : (_Float16)0.f;
  } else if (idx < NGP * DD + NG * DD) {  // WhT
    int i2 = idx - NGP * DD;
    int col = i2 >> 7, k = i2 & 127;
    WhT[i2] = (_Float16)Wh[k * NG + col];
  } else if (idx < NGP * DD + NG * DD + NGP) {  // bias_p
    int pcol = idx - NGP * DD - NG * DD;
    int u = pcol >> 3, g = pcol & 7;
    bias_p[pcol] = (g < 7) ? bias[g * HH + u] : 0.f;
  }
}

// xg GEMM, A-tile staged once per block (coalesced), nt-loop inside.
__global__ __launch_bounds__(256, 2) void xg_gemm_k(const float* __restrict__ x,
    const _Float16* __restrict__ WxTp, const float* __restrict__ bias_p,
    _Float16* __restrict__ xg, int t0) {
  int mt = blockIdx.x;
  __shared__ _Float16 Ald[128][136];
  __shared__ _Float16 Bld[128][136];
  int tid = threadIdx.x;
  int G0 = mt * 128;
  int t = t0 + (G0 >> 8);
  int b0 = G0 & 255;
  {  // coalesced f32 load of x[b0..b0+128)[t][0..128) -> f16 in Ald
    int r = tid >> 5, kq = (tid & 31) << 2;
#pragma unroll
    for (int it = 0; it < 16; ++it) {
      int row = r + it * 8;
      float4v xv = *(const float4v*)(x + ((size_t)(b0 + row) * TT + t) * DD + kq);
      half4 h4 = {(_Float16)xv[0], (_Float16)xv[1], (_Float16)xv[2], (_Float16)xv[3]};
      *(half4*)&Ald[row][kq] = h4;
    }
  }
  __syncthreads();
  int wv = tid >> 6, l = tid & 63, lr = l & 15, lk8 = (l >> 4) << 3;
  half8 af[2][4];
#pragma unroll
  for (int mf = 0; mf < 2; ++mf)
#pragma unroll
    for (int kk = 0; kk < 4; ++kk)
      af[mf][kk] = *(const half8*)&Ald[wv * 32 + mf * 16 + lr][kk * 32 + lk8];

  for (int nt = 0; nt < 8; ++nt) {
    for (int i = tid; i < 128 * 16; i += 256) {
      int r = i >> 4, c8 = (i & 15) << 3;
      *(half8*)&Bld[r][c8] = *(const half8*)(WxTp + (size_t)(nt * 128 + r) * DD + c8);
    }
    __syncthreads();
    float4v acc[2][8];
#pragma unroll
    for (int a = 0; a < 2; ++a)
#pragma unroll
      for (int q = 0; q < 8; ++q) acc[a][q] = (float4v){0.f, 0.f, 0.f, 0.f};
#pragma unroll
    for (int kk = 0; kk < 4; ++kk) {
#pragma unroll
      for (int nf = 0; nf < 8; ++nf) {
        half8 bv = *(const half8*)&Bld[nf * 16 + lr][kk * 32 + lk8];
        acc[0][nf] = __builtin_amdgcn_mfma_f32_16x16x32_f16(af[0][kk], bv, acc[0][nf], 0, 0, 0);
        acc[1][nf] = __builtin_amdgcn_mfma_f32_16x16x32_f16(af[1][kk], bv, acc[1][nf], 0, 0, 0);
      }
    }
    int r4 = (l >> 4) << 2;
#pragma unroll
    for (int nf = 0; nf < 8; ++nf) {
      int col = nt * 128 + nf * 16 + lr;
      float bv = bias_p[col];
#pragma unroll
      for (int mf = 0; mf < 2; ++mf) {
        int row = G0 + wv * 32 + mf * 16 + r4;
#pragma unroll
        for (int rr = 0; rr < 4; ++rr) {
          xg[(size_t)(row + rr) * NGP + col] = (_Float16)(acc[mf][nf][rr] + bv);
        }
      }
    }
    __syncthreads();  // before next nt overwrites Bld
  }
}

// MFMA recurrence (r5 structure): 1 block/sample, 512 threads (8 waves).
// Wave w, lane l: lr=l&15, lg=l>>4, unit u=w*16+lr. A = h broadcast to all 16
// rows => acc[tt][0] = gate-tt preactivation for unit u. Each lane does the
// full state update for its unit (4x replicated over lg); lg==0 writes
// h/outputs. NEW: 8-step register-batched xg prefetch — loads issued once per
// 8 steps at batch top, so only the first of 8 __syncthreads (which drain
// vmcnt) pays the HBM-latency tail; the other 7 have nothing outstanding.
__global__ __launch_bounds__(512, 2) void rec_k(const _Float16* __restrict__ xg,
    const float* __restrict__ dur, const int* __restrict__ rep,
    const _Float16* __restrict__ WhT, float* __restrict__ out,
    _Float16* __restrict__ st_h, float* __restrict__ st_c, float* __restrict__ st_cb,
    int t0, int t1) {
  int b = blockIdx.x, j = threadIdx.x;
  int tend = rep[b];
  if (t0 > tend) return;  // block-uniform
  int tstop = min(t1 - 1, tend);
  __shared__ __align__(16) _Float16 hbuf[2][HH];
  __shared__ float dlds[TT];
  int w = j >> 6, l = j & 63, lr = l & 15, lg = l >> 4;
  int u = w * 16 + lr;

  // B-fragments: wb[tt][kk] = WhT[col = tt*128+u][k = kk*32 + lg*8 .. +8]
  half8 wb[7][4];
#pragma unroll
  for (int tt = 0; tt < 7; ++tt) {
#pragma unroll
    for (int kk = 0; kk < 4; ++kk)
      wb[tt][kk] = *(const half8*)(WhT + (size_t)(tt * HH + u) * DD + kk * 32 + lg * 8);
  }
  for (int i = j; i < TT; i += 512) dlds[i] = dur[b * TT + i];
  float c_s = 0.f, cb_s = 0.f;
  if (lg == 0) {
    if (t0 == 0) {
      hbuf[0][u] = (_Float16)0.f;
    } else {
      hbuf[0][u] = st_h[b * HH + u];
    }
    hbuf[1][u] = (_Float16)0.f;
  }
  if (t0 != 0) {
    c_s = st_c[b * HH + u];
    cb_s = st_cb[b * HH + u];
  }
  __syncthreads();

  const _Float16* xgp = xg + (size_t)b * NGP + u * 8;  // + step*stp, aligned 16B
  const size_t stp = (size_t)BB * NGP;
  half8 cur[8], nxt[8];
#pragma unroll
  for (int i = 0; i < 8; ++i)
    cur[i] = *(const half8*)(xgp + (size_t)(min(t0 + i, tstop) - t0) * stp);
  float hsave = 0.f;

#define STEP(T, CUR, PIN, POUT)                                                  \
  do {                                                                           \
    float dt = dlds[T];                                                          \
    half8 af[4];                                                                 \
    _Pragma("unroll") for (int kk = 0; kk < 4; ++kk)                             \
        af[kk] = *(const half8*)((const char*)hbuf[PIN] + kk * 64 + lg * 16);    \
    float4v acc[7];                                                              \
    _Pragma("unroll") for (int tt = 0; tt < 7; ++tt) {                           \
      float xv = (float)CUR[tt];                                                 \
      acc[tt] = (float4v){xv, xv, xv, xv};                                       \
    }                                                                            \
    _Pragma("unroll") for (int kk = 0; kk < 4; ++kk)                             \
        _Pragma("unroll") for (int tt = 0; tt < 7; ++tt)                         \
            acc[tt] = __builtin_amdgcn_mfma_f32_16x16x32_f16(af[kk], wb[tt][kk], \
                                                             acc[tt], 0, 0, 0);  \
    float iv = sigmoidf_(acc[0][0]), fv = sigmoidf_(acc[1][0]);                  \
    float zv = tanhf_(acc[2][0]), ov = sigmoidf_(acc[3][0]);                     \
    float ibv = sigmoidf_(acc[4][0]), fbv = sigmoidf_(acc[5][0]);                \
    float dv = softplusf_(acc[6][0]);                                            \
    float cc = fv * c_s + iv * zv;                                               \
    cb_s = fbv * cb_s + ibv * zv;                                                \
    float cn = cb_s + (cc - cb_s) * __expf(-dv * dt);                            \
    float hn = ov * tanhf_(cn);                                                  \
    c_s = cn;                                                                    \
    hsave = hn;                                                                  \
    if (lg == 0) {                                                               \
      if ((T) == tend) {                                                         \
        out[b * HH + u] = hn;                                                    \
        out[BB * HH + b * HH + u] = cn;                                          \
      }                                                                          \
      hbuf[POUT][u] = (_Float16)hn;                                              \
    }                                                                            \
    __syncthreads();                                                             \
  } while (0)

  for (int tb = t0; tb <= tstop; tb += 8) {
    // issue next batch's 8 loads up front; first STEP's barrier drains them once
#pragma unroll
    for (int i = 0; i < 8; ++i)
      nxt[i] = *(const half8*)(xgp + (size_t)(min(tb + 8 + i, tstop) - t0) * stp);
    STEP(tb, cur[0], 0, 1);
    if (tb + 1 <= tstop) STEP(tb + 1, cur[1], 1, 0);
    if (tb + 2 <= tstop) STEP(tb + 2, cur[2], 0, 1);
    if (tb + 3 <= tstop) STEP(tb + 3, cur[3], 1, 0);
    if (tb + 4 <= tstop) STEP(tb + 4, cur[4], 0, 1);
    if (tb + 5 <= tstop) STEP(tb + 5, cur[5], 1, 0);
    if (tb + 6 <= tstop) STEP(tb + 6, cur[6], 0, 1);
    if (tb + 7 <= tstop) STEP(tb + 7, cur[7], 1, 0);
#pragma unroll
    for (int i = 0; i < 8; ++i) cur[i] = nxt[i];
  }
#undef STEP

  if (tstop < tend && lg == 0) {  // save state for next chunk
    st_h[b * HH + u] = (_Float16)hsave;
    st_c[b * HH + u] = c_s;
    st_cb[b * HH + u] = cb_s;
  }
}

extern "C" void kernel_launch(void* const* d_in, const int* in_sizes, int n_in,
                              void* d_out, int out_size, void* d_ws, size_t ws_size,
                              hipStream_t stream) {
  const float* x = (const float*)d_in[0];
  const float* dur = (const float*)d_in[1];
  const int* rep = (const int*)d_in[2];
  const float* Wx = (const float*)d_in[3];
  const float* Wh = (const float*)d_in[4];
  const float* bias = (const float*)d_in[5];
  float* out = (float*)d_out;
  char* ws = (char*)d_ws;

  size_t off = 0;
  _Float16* WxTp = (_Float16*)(ws + off); off += (size_t)NGP * DD * 2;
  _Float16* WhT = (_Float16*)(ws + off); off += (size_t)NG * DD * 2;
  float* bias_p = (float*)(ws + off); off += (size_t)NGP * 4;
  _Float16* st_h = (_Float16*)(ws + off); off += (size_t)BB * HH * 2;
  float* st_c = (float*)(ws + off); off += (size_t)BB * HH * 4;
  float* st_cb = (float*)(ws + off); off += (size_t)BB * HH * 4;
  _Float16* xgbuf = (_Float16*)(ws + off);

  size_t avail = ws_size > off ? ws_size - off : 0;
  size_t perT = (size_t)BB * NGP * 2;
  int Tc = (int)(avail / perT);
  if (Tc > TT) Tc = TT;
  if (Tc < 1) Tc = 1;

  int nprep = NGP * DD + NG * DD + NGP;
  hipLaunchKernelGGL(wtrans_k, dim3((nprep + 255) / 256), dim3(256), 0, stream,
                     Wx, Wh, bias, WxTp, WhT, bias_p);
  for (int t0 = 0; t0 < TT; t0 += Tc) {
    int t1 = t0 + Tc;
    if (t1 > TT) t1 = TT;
    int mtiles = (t1 - t0) * BB / 128;
    hipLaunchKernelGGL(xg_gemm_k, dim3(mtiles), dim3(256), 0, stream,
                       x, WxTp, bias_p, xgbuf, t0);
    hipLaunchKernelGGL(rec_k, dim3(BB), dim3(512), 0, stream,
                       xgbuf, dur, rep, WhT, out, st_h, st_c, st_cb, t0, t1);
  }
}